// Round 2
// baseline (212.761 us; speedup 1.0000x reference)
//
#include <hip/hip_runtime.h>

#define NNODES 100000
#define NEDGES 640000
#define HDIM 128
#define CDIM 16
#define NP 100352           // NNODES padded
#define SLOTS 32            // per-node bucket capacity; true max degree ~23 (Poisson 6.4)

typedef __attribute__((ext_vector_type(8))) short bf16x8;
typedef __attribute__((ext_vector_type(4))) float f32x4;

union U16x8 { uint4 u; bf16x8 v; };

__device__ __forceinline__ unsigned short f2bf(float f) {
    unsigned int u = __float_as_uint(f);
    unsigned int r = (u + 0x7fffu + ((u >> 16) & 1u)) >> 16;   // RNE
    return (unsigned short)r;
}
__device__ __forceinline__ float bf2f(unsigned short s) {
    return __uint_as_float(((unsigned int)s) << 16);
}

__device__ __forceinline__ void acc8(float (&a)[8], uint4 u) {
    a[0] += bf2f(u.x & 0xffff); a[1] += bf2f(u.x >> 16);
    a[2] += bf2f(u.y & 0xffff); a[3] += bf2f(u.y >> 16);
    a[4] += bf2f(u.z & 0xffff); a[5] += bf2f(u.z >> 16);
    a[6] += bf2f(u.w & 0xffff); a[7] += bf2f(u.w >> 16);
}

// 12500 blocks; every block converts its x->bf16 slice. Every 5th block ALSO
// bins a 256-edge chunk (atomic issued before cvt so its latency hides under
// the BW-bound cvt loads). Blocks b%5==1 (first 144 of them) build W images.
// W1 image is TWO 32KB half-images (W1l then W1r), each n*128-swizzled,
// so the fused GEMM can swap halves through one 32KB LDS region.
__global__ __launch_bounds__(256) void binfuse_kernel(
    const int* __restrict__ src, const int* __restrict__ dst,
    int* __restrict__ cnt, int* __restrict__ ebuf,
    const float* __restrict__ x, unsigned short* __restrict__ xb,
    const float* __restrict__ W1l, const float* __restrict__ W1r,
    const float* __restrict__ W2l, const float* __restrict__ W2r,
    unsigned short* __restrict__ w1img, unsigned short* __restrict__ w2img)
{
    const int b = blockIdx.x;
    const int tid = threadIdx.x;
    const int m5 = b % 5;

    // start the scattered atomic chain early
    int d = 0, s = 0, p = SLOTS;
    if (m5 == 0) {
        int e = (b / 5) * 256 + tid;             // 2500 chunks x 256 = 640k exactly
        d = dst[e];
        s = src[e];
        p = atomicAdd(&cnt[d], 1);
    }

    // cvt slice (all blocks): 12500 x 256 = 3.2M float4 units exactly
    {
        int i = b * 256 + tid;
        float4 v = reinterpret_cast<const float4*>(x)[i];
        ushort4 r;
        r.x = f2bf(v.x); r.y = f2bf(v.y); r.z = f2bf(v.z); r.w = f2bf(v.w);
        reinterpret_cast<ushort4*>(xb)[i] = r;
    }

    if (m5 == 0) {
        if (p < SLOTS) ebuf[d * SLOTS + p] = s;
    } else if (m5 == 1 && b < 5 * 144) {
        int idx = (b / 5) * 256 + tid;           // 144 x 256 = 36864
        if (idx < 32768) {
            int n = idx >> 8;          // 0..127 output col
            int k = idx & 255;         // 0..255 concatenated K
            int half = k >> 7;         // 0 -> W1l, 1 -> W1r
            int kk = k & 127;
            float v = half ? W1r[kk * HDIM + n] : W1l[kk * HDIM + n];
            int ck = kk >> 3;
            w1img[half * 16384 + n * 128 + ((ck ^ (n & 7)) << 3) + (kk & 7)] = f2bf(v);
        } else {
            int rem = idx - 32768;
            int n = rem >> 7;
            int k = rem & 127;
            float v = (n < 16) ? W2l[k * CDIM + n] : W2r[k * CDIM + (n - 16)];
            int ck = k >> 3;
            w2img[n * 128 + ((ck ^ (n & 7)) << 3) + (k & 7)] = f2bf(v);
        }
    }
}

// Fused layer-1 gather + layer-1 GEMM + layer-2 projection per 128-row tile.
// LDS: one 32KB region (LW) time-shared W1l -> W1r -> h(swizzled), plus an
// 8KB W2 buffer. 40KB/block -> grid (782 blocks) nearly fully co-resident,
// vs R1's 66KB -> 2 blocks/CU -> 27% occupancy (latency-bound gather).
__global__ __launch_bounds__(512, 6) void gemm_fused_kernel(
    const unsigned short* __restrict__ xb, const int* __restrict__ cnt,
    const int* __restrict__ ebuf,
    const unsigned short* __restrict__ w1img, const unsigned short* __restrict__ w2img,
    const float* __restrict__ b1, const float* __restrict__ b2,
    float* __restrict__ pq)
{
    __shared__ alignas(16) unsigned short LW[128 * 128];   // 32 KB: W1l -> W1r -> h
    __shared__ alignas(16) unsigned short W2s[32 * 128];   // 8 KB: W2cat image

    const int tid = threadIdx.x;
    const int wave = tid >> 6;        // 0..7
    const int lane = tid & 63;
    const int lm = lane & 15;
    const int lq = lane >> 4;
    const int row0 = blockIdx.x * 128;
    const int row = row0 + wave * 16 + lm;
    const bool valid = row < NNODES;

    // stage W1l image into LW (2048 uint4) — overlaps with the gather below
    {
        const uint4* wsrc = reinterpret_cast<const uint4*>(w1img);
        uint4* wdst = reinterpret_cast<uint4*>(LW);
        #pragma unroll
        for (int j = 0; j < 4; ++j) wdst[tid + j * 512] = wsrc[tid + j * 512];
    }

    const uint4* xbv = reinterpret_cast<const uint4*>(xb);

    // ---- per-thread neighbor mean: 4 lanes (lq=0..3) cover each row ----
    float ag[4][8];
    #pragma unroll
    for (int kt = 0; kt < 4; ++kt) {
        #pragma unroll
        for (int i = 0; i < 8; ++i) ag[kt][i] = 0.0f;
    }
    int deg = 0;
    if (valid) {
        deg = cnt[row];
        int n = min(deg, SLOTS);
        const int* eb = ebuf + row * SLOTS;
        int j = 0;
        for (; j + 1 < n; j += 2) {
            int2 ss = *reinterpret_cast<const int2*>(eb + j);
            size_t b0 = (size_t)ss.x * 16 + lq;
            size_t b1v = (size_t)ss.y * 16 + lq;
            #pragma unroll
            for (int kt = 0; kt < 4; ++kt) {
                uint4 u = xbv[b0 + kt * 4];
                uint4 v = xbv[b1v + kt * 4];
                acc8(ag[kt], u);
                acc8(ag[kt], v);
            }
        }
        if (j < n) {
            int s0 = eb[j];
            size_t b0 = (size_t)s0 * 16 + lq;
            #pragma unroll
            for (int kt = 0; kt < 4; ++kt) acc8(ag[kt], xbv[b0 + kt * 4]);
        }
    }
    const float sc = 1.0f / fmaxf((float)deg, 1.0f);

    U16x8 af[8];
    #pragma unroll
    for (int kt = 0; kt < 4; ++kt) {
        uint4 r;
        r.x = (unsigned)f2bf(ag[kt][0] * sc) | ((unsigned)f2bf(ag[kt][1] * sc) << 16);
        r.y = (unsigned)f2bf(ag[kt][2] * sc) | ((unsigned)f2bf(ag[kt][3] * sc) << 16);
        r.z = (unsigned)f2bf(ag[kt][4] * sc) | ((unsigned)f2bf(ag[kt][5] * sc) << 16);
        r.w = (unsigned)f2bf(ag[kt][6] * sc) | ((unsigned)f2bf(ag[kt][7] * sc) << 16);
        af[kt].u = r;
    }
    // x fragments for the second K-half (in flight across stage 1a)
    {
        uint4 z = make_uint4(0u, 0u, 0u, 0u);
        size_t abase = (size_t)row * 16 + lq;
        #pragma unroll
        for (int kt = 0; kt < 4; ++kt) af[4 + kt].u = valid ? xbv[abase + kt * 4] : z;
    }

    float bv[8];
    #pragma unroll
    for (int ct = 0; ct < 8; ++ct) bv[ct] = b1[ct * 16 + lm];
    const float bq = b2[lm];

    f32x4 acc[8];
    #pragma unroll
    for (int c = 0; c < 8; ++c) acc[c] = (f32x4)(0.0f);

    __syncthreads();   // LW = W1l ready

    // ---- stage 1a: K 0..127 (agg half) ----
    #pragma unroll
    for (int kt = 0; kt < 4; ++kt) {
        int c = kt * 4 + lq;
        #pragma unroll
        for (int ct = 0; ct < 8; ++ct) {
            int n = ct * 16 + lm;
            bf16x8 bfrag = *reinterpret_cast<const bf16x8*>(&LW[n * 128 + ((c ^ (n & 7)) << 3)]);
            acc[ct] = __builtin_amdgcn_mfma_f32_16x16x32_bf16(af[kt].v, bfrag, acc[ct], 0, 0, 0);
        }
    }
    __syncthreads();   // all waves done reading W1l

    // swap in W1r; stage W2 image into its own buffer (once)
    {
        const uint4* wsrc = reinterpret_cast<const uint4*>(w1img + 16384);
        uint4* wdst = reinterpret_cast<uint4*>(LW);
        #pragma unroll
        for (int j = 0; j < 4; ++j) wdst[tid + j * 512] = wsrc[tid + j * 512];
        uint4 w = reinterpret_cast<const uint4*>(w2img)[tid];   // 512 x 16B = 8 KB
        reinterpret_cast<uint4*>(W2s)[tid] = w;
    }
    __syncthreads();   // LW = W1r ready

    // ---- stage 1b: K 128..255 (x half) ----
    #pragma unroll
    for (int kt = 0; kt < 4; ++kt) {
        int c = kt * 4 + lq;
        #pragma unroll
        for (int ct = 0; ct < 8; ++ct) {
            int n = ct * 16 + lm;
            bf16x8 bfrag = *reinterpret_cast<const bf16x8*>(&LW[n * 128 + ((c ^ (n & 7)) << 3)]);
            acc[ct] = __builtin_amdgcn_mfma_f32_16x16x32_bf16(af[4 + kt].v, bfrag, acc[ct], 0, 0, 0);
        }
    }
    __syncthreads();   // done reading W1r; LW reusable

    // h -> LW (bf16), XOR-swizzled, stride 128 shorts:
    // h[r][c] lives at LW[r*128 + (((c>>3) ^ (r&7))<<3) + (c&7)]
    #pragma unroll
    for (int i = 0; i < 4; ++i) {
        int r = wave * 16 + lq * 4 + i;
        #pragma unroll
        for (int ct = 0; ct < 8; ++ct) {
            int c = ct * 16 + lm;
            float v = fmaxf(acc[ct][i] + bv[ct], 0.0f);
            LW[r * 128 + (((c >> 3) ^ (r & 7)) << 3) + (c & 7)] = f2bf(v);
        }
    }
    __syncthreads();   // h + W2 ready

    // ---- stage 2: pq-tile = h @ W2cat ----
    {
        const int arow = wave * 16 + lm;

        U16x8 a2[4];
        #pragma unroll
        for (int kt = 0; kt < 4; ++kt) {
            int ck = kt * 4 + lq;                 // 8-aligned col block of h
            a2[kt].v = *reinterpret_cast<const bf16x8*>(&LW[arow * 128 + ((ck ^ (arow & 7)) << 3)]);
        }

        f32x4 acc2[2];
        acc2[0] = (f32x4)(0.0f);
        acc2[1] = (f32x4)(0.0f);

        #pragma unroll
        for (int kt = 0; kt < 4; ++kt) {
            int c = kt * 4 + lq;
            #pragma unroll
            for (int ct = 0; ct < 2; ++ct) {
                int n = ct * 16 + lm;
                bf16x8 bfrag = *reinterpret_cast<const bf16x8*>(&W2s[n * 128 + ((c ^ (n & 7)) << 3)]);
                acc2[ct] = __builtin_amdgcn_mfma_f32_16x16x32_bf16(a2[kt].v, bfrag, acc2[ct], 0, 0, 0);
            }
        }

        #pragma unroll
        for (int ct = 0; ct < 2; ++ct) {
            int col = ct * 16 + lm;
            float bvv = (ct == 1) ? bq : 0.0f;
            #pragma unroll
            for (int i = 0; i < 4; ++i) {
                int r = row0 + wave * 16 + lq * 4 + i;
                if (r < NNODES)
                    pq[(size_t)r * 32 + col] = acc2[ct][i] + bvv;
            }
        }
    }
}

// layer-2 fused: out[node] = inv * sum_{src} p[src] + q[node]
__global__ __launch_bounds__(256) void gather2_kernel(
    const float* __restrict__ pq, const int* __restrict__ cnt,
    const int* __restrict__ ebuf, float* __restrict__ out)
{
    int t = blockIdx.x * blockDim.x + threadIdx.x;
    int node = t >> 2;
    int c = t & 3;
    if (node >= NNODES) return;
    int deg = cnt[node];
    int n = min(deg, SLOTS);
    const int* eb = ebuf + node * SLOTS;
    float ax = 0.f, ay = 0.f, az = 0.f, aw = 0.f;
    int j = 0;
    for (; j + 1 < n; j += 2) {
        int2 ss = *reinterpret_cast<const int2*>(eb + j);
        float4 v0 = reinterpret_cast<const float4*>(pq)[ss.x * 8 + c];
        float4 v1 = reinterpret_cast<const float4*>(pq)[ss.y * 8 + c];
        ax += v0.x + v1.x; ay += v0.y + v1.y; az += v0.z + v1.z; aw += v0.w + v1.w;
    }
    if (j < n) {
        int s0 = eb[j];
        float4 v0 = reinterpret_cast<const float4*>(pq)[s0 * 8 + c];
        ax += v0.x; ay += v0.y; az += v0.z; aw += v0.w;
    }
    float sc = 1.0f / fmaxf((float)deg, 1.0f);
    float4 q = reinterpret_cast<const float4*>(pq)[node * 8 + 4 + c];
    float4 r;
    r.x = ax * sc + q.x; r.y = ay * sc + q.y; r.z = az * sc + q.z; r.w = aw * sc + q.w;
    reinterpret_cast<float4*>(out)[node * 4 + c] = r;
}

extern "C" void kernel_launch(void* const* d_in, const int* in_sizes, int n_in,
                              void* d_out, int out_size, void* d_ws, size_t ws_size,
                              hipStream_t stream) {
    const float* x   = (const float*)d_in[0];
    const int*   ei  = (const int*)d_in[1];
    const float* W1l = (const float*)d_in[2];
    const float* W1r = (const float*)d_in[3];
    const float* b1  = (const float*)d_in[4];
    const float* W2l = (const float*)d_in[5];
    const float* W2r = (const float*)d_in[6];
    const float* b2  = (const float*)d_in[7];
    float* out = (float*)d_out;

    const int* src = ei;
    const int* dst = ei + NEDGES;

    // workspace layout (agg buffer eliminated)
    int* cnt  = (int*)d_ws;                                                 // NP ints (degree)
    int* ebuf = cnt + NP;                                                   // N*SLOTS ints (12.8 MB)
    unsigned short* xb  = (unsigned short*)(ebuf + (size_t)NNODES * SLOTS); // N*128 bf16
    float* pq = (float*)(xb + (size_t)NNODES * HDIM);                       // N*32 f32
    unsigned short* w1img = (unsigned short*)(pq + (size_t)NNODES * 32);    // 32768 bf16 (2 halves)
    unsigned short* w2img = w1img + 32768;                                  // 4096 bf16

    hipMemsetAsync(cnt, 0, NP * sizeof(int), stream);

    binfuse_kernel<<<12500, 256, 0, stream>>>(src, dst, cnt, ebuf, x, xb,
                                              W1l, W1r, W2l, W2r, w1img, w2img);

    int ntiles1 = (NNODES + 127) / 128;   // 782
    gemm_fused_kernel<<<ntiles1, 512, 0, stream>>>(xb, cnt, ebuf, w1img, w2img, b1, b2, pq);

    gather2_kernel<<<(NNODES * 4 + 255) / 256, 256, 0, stream>>>(pq, cnt, ebuf, out);
}

// Round 4
// 186.927 us; speedup vs baseline: 1.1382x; 1.1382x over previous
//
#include <hip/hip_runtime.h>

#define NNODES 100000
#define NEDGES 640000
#define HDIM 128
#define CDIM 16
#define NP 100352           // NNODES padded
#define SLOTS 32            // per-node bucket capacity; true max degree ~23 (Poisson 6.4)

typedef __attribute__((ext_vector_type(8))) short bf16x8;
typedef __attribute__((ext_vector_type(4))) float f32x4;

union U16x8 { uint4 u; bf16x8 v; };

__device__ __forceinline__ unsigned short f2bf(float f) {
    unsigned int u = __float_as_uint(f);
    unsigned int r = (u + 0x7fffu + ((u >> 16) & 1u)) >> 16;   // RNE
    return (unsigned short)r;
}
__device__ __forceinline__ float bf2f(unsigned short s) {
    return __uint_as_float(((unsigned int)s) << 16);
}

__device__ __forceinline__ void acc8(float (&a)[8], uint4 u) {
    a[0] += bf2f(u.x & 0xffff); a[1] += bf2f(u.x >> 16);
    a[2] += bf2f(u.y & 0xffff); a[3] += bf2f(u.y >> 16);
    a[4] += bf2f(u.z & 0xffff); a[5] += bf2f(u.z >> 16);
    a[6] += bf2f(u.w & 0xffff); a[7] += bf2f(u.w >> 16);
}

// 12500 blocks; every block converts its x->bf16 slice. Every 5th block ALSO
// bins a 256-edge chunk. Blocks b%5==1 (first 144 of them) build W images.
// W1 image is TWO 32KB half-images (W1l then W1r), each n*128-swizzled;
// each half is further consumed in contiguous 16KB n-quarters by the GEMM.
__global__ __launch_bounds__(256) void binfuse_kernel(
    const int* __restrict__ src, const int* __restrict__ dst,
    int* __restrict__ cnt, int* __restrict__ ebuf,
    const float* __restrict__ x, unsigned short* __restrict__ xb,
    const float* __restrict__ W1l, const float* __restrict__ W1r,
    const float* __restrict__ W2l, const float* __restrict__ W2r,
    unsigned short* __restrict__ w1img, unsigned short* __restrict__ w2img)
{
    const int b = blockIdx.x;
    const int tid = threadIdx.x;
    const int m5 = b % 5;

    // start the scattered atomic chain early
    int d = 0, s = 0, p = SLOTS;
    if (m5 == 0) {
        int e = (b / 5) * 256 + tid;             // 2500 chunks x 256 = 640k exactly
        d = dst[e];
        s = src[e];
        p = atomicAdd(&cnt[d], 1);
    }

    // cvt slice (all blocks): 12500 x 256 = 3.2M float4 units exactly
    {
        int i = b * 256 + tid;
        float4 v = reinterpret_cast<const float4*>(x)[i];
        ushort4 r;
        r.x = f2bf(v.x); r.y = f2bf(v.y); r.z = f2bf(v.z); r.w = f2bf(v.w);
        reinterpret_cast<ushort4*>(xb)[i] = r;
    }

    if (m5 == 0) {
        if (p < SLOTS) ebuf[d * SLOTS + p] = s;
    } else if (m5 == 1 && b < 5 * 144) {
        int idx = (b / 5) * 256 + tid;           // 144 x 256 = 36864
        if (idx < 32768) {
            int n = idx >> 8;          // 0..127 output col
            int k = idx & 255;         // 0..255 concatenated K
            int half = k >> 7;         // 0 -> W1l, 1 -> W1r
            int kk = k & 127;
            float v = half ? W1r[kk * HDIM + n] : W1l[kk * HDIM + n];
            int ck = kk >> 3;
            w1img[half * 16384 + n * 128 + ((ck ^ (n & 7)) << 3) + (kk & 7)] = f2bf(v);
        } else {
            int rem = idx - 32768;
            int n = rem >> 7;
            int k = rem & 127;
            float v = (n < 16) ? W2l[k * CDIM + n] : W2r[k * CDIM + (n - 16)];
            int ck = k >> 3;
            w2img[n * 128 + ((ck ^ (n & 7)) << 3) + (k & 7)] = f2bf(v);
        }
    }
}

// Fused layer-1 gather + layer-1 GEMM + layer-2 projection per 64-row tile.
// 256 threads / 4 waves; W1 streamed through ONE 16KB LDS buffer in four
// 16KB n-quarters (W1l.n0, W1l.n1, W1r.n0, W1r.n1); h reuses the same 16KB.
// LDS = 24KB/block -> up to 6 blocks/CU; occupancy is VGPR-bound (~5 blocks).
// x-fragments are loaded AFTER the agg-half MFMAs so ag/af_agg die first:
// peak liveness ~75 regs, no launch_bounds cap that would force spills (R2).
__global__ __launch_bounds__(256, 4) void gemm_fused_kernel(
    const unsigned short* __restrict__ xb, const int* __restrict__ cnt,
    const int* __restrict__ ebuf,
    const unsigned short* __restrict__ w1img, const unsigned short* __restrict__ w2img,
    const float* __restrict__ b1, const float* __restrict__ b2,
    float* __restrict__ pq)
{
    __shared__ alignas(16) unsigned short LW[64 * 128];    // 16 KB: W1 quarter -> h
    __shared__ alignas(16) unsigned short W2s[32 * 128];   // 8 KB: W2cat image

    const int tid = threadIdx.x;
    const int wave = tid >> 6;        // 0..3
    const int lane = tid & 63;
    const int lm = lane & 15;
    const int lq = lane >> 4;
    const int row0 = blockIdx.x * 64;
    const int row = row0 + wave * 16 + lm;
    const bool valid = row < NNODES;

    const uint4* w1v = reinterpret_cast<const uint4*>(w1img);   // 4096 uint4, quarters of 1024
    uint4* lwv = reinterpret_cast<uint4*>(LW);

    // stage W1l.n0 (quarter 0) — overlaps with the gather below
    #pragma unroll
    for (int j = 0; j < 4; ++j) lwv[tid + j * 256] = w1v[tid + j * 256];

    const uint4* xbv = reinterpret_cast<const uint4*>(xb);

    // ---- per-thread neighbor mean: 4 lanes (lq=0..3) cover each row ----
    float ag[4][8];
    #pragma unroll
    for (int kt = 0; kt < 4; ++kt) {
        #pragma unroll
        for (int i = 0; i < 8; ++i) ag[kt][i] = 0.0f;
    }
    int deg = 0;
    if (valid) {
        deg = cnt[row];
        int n = min(deg, SLOTS);
        const int* eb = ebuf + row * SLOTS;
        int j = 0;
        for (; j + 1 < n; j += 2) {
            int2 ss = *reinterpret_cast<const int2*>(eb + j);
            size_t b0 = (size_t)ss.x * 16 + lq;
            size_t b1v = (size_t)ss.y * 16 + lq;
            #pragma unroll
            for (int kt = 0; kt < 4; ++kt) {
                uint4 u = xbv[b0 + kt * 4];
                uint4 v = xbv[b1v + kt * 4];
                acc8(ag[kt], u);
                acc8(ag[kt], v);
            }
        }
        if (j < n) {
            int s0 = eb[j];
            size_t b0 = (size_t)s0 * 16 + lq;
            #pragma unroll
            for (int kt = 0; kt < 4; ++kt) acc8(ag[kt], xbv[b0 + kt * 4]);
        }
    }
    const float sc = 1.0f / fmaxf((float)deg, 1.0f);

    // pack agg A-fragments (ag dies here)
    U16x8 af[4];
    #pragma unroll
    for (int kt = 0; kt < 4; ++kt) {
        uint4 r;
        r.x = (unsigned)f2bf(ag[kt][0] * sc) | ((unsigned)f2bf(ag[kt][1] * sc) << 16);
        r.y = (unsigned)f2bf(ag[kt][2] * sc) | ((unsigned)f2bf(ag[kt][3] * sc) << 16);
        r.z = (unsigned)f2bf(ag[kt][4] * sc) | ((unsigned)f2bf(ag[kt][5] * sc) << 16);
        r.w = (unsigned)f2bf(ag[kt][6] * sc) | ((unsigned)f2bf(ag[kt][7] * sc) << 16);
        af[kt].u = r;
    }

    float bv[8];
    #pragma unroll
    for (int ct = 0; ct < 8; ++ct) bv[ct] = b1[ct * 16 + lm];
    const float bq = b2[lm];

    f32x4 acc[8];
    #pragma unroll
    for (int c = 0; c < 8; ++c) acc[c] = (f32x4)(0.0f);

    __syncthreads();   // LW = W1l.n0

    // ---- agg half (K 0..127) x n-quarter 0 (ct 0..3) ----
    #pragma unroll
    for (int kt = 0; kt < 4; ++kt) {
        int c = kt * 4 + lq;
        #pragma unroll
        for (int ct = 0; ct < 4; ++ct) {
            int nl = ct * 16 + lm;
            bf16x8 bfrag = *reinterpret_cast<const bf16x8*>(&LW[nl * 128 + ((c ^ (lm & 7)) << 3)]);
            acc[ct] = __builtin_amdgcn_mfma_f32_16x16x32_bf16(af[kt].v, bfrag, acc[ct], 0, 0, 0);
        }
    }
    __syncthreads();
    #pragma unroll
    for (int j = 0; j < 4; ++j) lwv[tid + j * 256] = w1v[1024 + tid + j * 256];   // W1l.n1
    __syncthreads();

    // ---- agg half x n-quarter 1 (ct 4..7) ----
    #pragma unroll
    for (int kt = 0; kt < 4; ++kt) {
        int c = kt * 4 + lq;
        #pragma unroll
        for (int ct = 4; ct < 8; ++ct) {
            int nl = (ct - 4) * 16 + lm;
            bf16x8 bfrag = *reinterpret_cast<const bf16x8*>(&LW[nl * 128 + ((c ^ (lm & 7)) << 3)]);
            acc[ct] = __builtin_amdgcn_mfma_f32_16x16x32_bf16(af[kt].v, bfrag, acc[ct], 0, 0, 0);
        }
    }
    __syncthreads();
    {
        #pragma unroll
        for (int j = 0; j < 4; ++j) lwv[tid + j * 256] = w1v[2048 + tid + j * 256]; // W1r.n0
        // W2 image (512 uint4) into its own buffer, once
        reinterpret_cast<uint4*>(W2s)[tid]       = reinterpret_cast<const uint4*>(w2img)[tid];
        reinterpret_cast<uint4*>(W2s)[tid + 256] = reinterpret_cast<const uint4*>(w2img)[tid + 256];
    }
    // x fragments for the second K-half (af_agg slots reused; ag already dead)
    {
        uint4 z = make_uint4(0u, 0u, 0u, 0u);
        size_t abase = (size_t)row * 16 + lq;
        #pragma unroll
        for (int kt = 0; kt < 4; ++kt) af[kt].u = valid ? xbv[abase + kt * 4] : z;
    }
    __syncthreads();

    // ---- x half (K 128..255) x n-quarter 0 (ct 0..3) ----
    #pragma unroll
    for (int kt = 0; kt < 4; ++kt) {
        int c = kt * 4 + lq;
        #pragma unroll
        for (int ct = 0; ct < 4; ++ct) {
            int nl = ct * 16 + lm;
            bf16x8 bfrag = *reinterpret_cast<const bf16x8*>(&LW[nl * 128 + ((c ^ (lm & 7)) << 3)]);
            acc[ct] = __builtin_amdgcn_mfma_f32_16x16x32_bf16(af[kt].v, bfrag, acc[ct], 0, 0, 0);
        }
    }
    __syncthreads();
    #pragma unroll
    for (int j = 0; j < 4; ++j) lwv[tid + j * 256] = w1v[3072 + tid + j * 256];   // W1r.n1
    __syncthreads();

    // ---- x half x n-quarter 1 (ct 4..7) ----
    #pragma unroll
    for (int kt = 0; kt < 4; ++kt) {
        int c = kt * 4 + lq;
        #pragma unroll
        for (int ct = 4; ct < 8; ++ct) {
            int nl = (ct - 4) * 16 + lm;
            bf16x8 bfrag = *reinterpret_cast<const bf16x8*>(&LW[nl * 128 + ((c ^ (lm & 7)) << 3)]);
            acc[ct] = __builtin_amdgcn_mfma_f32_16x16x32_bf16(af[kt].v, bfrag, acc[ct], 0, 0, 0);
        }
    }
    __syncthreads();   // done reading W1; LW reusable for h

    // h -> LW (bf16), XOR-swizzled, stride 128 shorts:
    // h[r][c] lives at LW[r*128 + (((c>>3) ^ (r&7))<<3) + (c&7)], r in 0..63
    #pragma unroll
    for (int i = 0; i < 4; ++i) {
        int r = wave * 16 + lq * 4 + i;
        #pragma unroll
        for (int ct = 0; ct < 8; ++ct) {
            int c = ct * 16 + lm;
            float v = fmaxf(acc[ct][i] + bv[ct], 0.0f);
            LW[r * 128 + (((c >> 3) ^ (r & 7)) << 3) + (c & 7)] = f2bf(v);
        }
    }
    __syncthreads();   // h + W2 ready

    // ---- stage 2: pq-tile = h @ W2cat ----
    {
        const int arow = wave * 16 + lm;    // 0..63

        U16x8 a2[4];
        #pragma unroll
        for (int kt = 0; kt < 4; ++kt) {
            int ck = kt * 4 + lq;
            a2[kt].v = *reinterpret_cast<const bf16x8*>(&LW[arow * 128 + ((ck ^ (arow & 7)) << 3)]);
        }

        f32x4 acc2[2];
        acc2[0] = (f32x4)(0.0f);
        acc2[1] = (f32x4)(0.0f);

        #pragma unroll
        for (int kt = 0; kt < 4; ++kt) {
            int c = kt * 4 + lq;
            #pragma unroll
            for (int ct = 0; ct < 2; ++ct) {
                int n = ct * 16 + lm;
                bf16x8 bfrag = *reinterpret_cast<const bf16x8*>(&W2s[n * 128 + ((c ^ (n & 7)) << 3)]);
                acc2[ct] = __builtin_amdgcn_mfma_f32_16x16x32_bf16(a2[kt].v, bfrag, acc2[ct], 0, 0, 0);
            }
        }

        #pragma unroll
        for (int ct = 0; ct < 2; ++ct) {
            int col = ct * 16 + lm;
            float bvv = (ct == 1) ? bq : 0.0f;
            #pragma unroll
            for (int i = 0; i < 4; ++i) {
                int r = row0 + wave * 16 + lq * 4 + i;
                if (r < NNODES)
                    pq[(size_t)r * 32 + col] = acc2[ct][i] + bvv;
            }
        }
    }
}

// layer-2 fused: out[node] = inv * sum_{src} p[src] + q[node]
__global__ __launch_bounds__(256) void gather2_kernel(
    const float* __restrict__ pq, const int* __restrict__ cnt,
    const int* __restrict__ ebuf, float* __restrict__ out)
{
    int t = blockIdx.x * blockDim.x + threadIdx.x;
    int node = t >> 2;
    int c = t & 3;
    if (node >= NNODES) return;
    int deg = cnt[node];
    int n = min(deg, SLOTS);
    const int* eb = ebuf + node * SLOTS;
    float ax = 0.f, ay = 0.f, az = 0.f, aw = 0.f;
    int j = 0;
    for (; j + 1 < n; j += 2) {
        int2 ss = *reinterpret_cast<const int2*>(eb + j);
        float4 v0 = reinterpret_cast<const float4*>(pq)[ss.x * 8 + c];
        float4 v1 = reinterpret_cast<const float4*>(pq)[ss.y * 8 + c];
        ax += v0.x + v1.x; ay += v0.y + v1.y; az += v0.z + v1.z; aw += v0.w + v1.w;
    }
    if (j < n) {
        int s0 = eb[j];
        float4 v0 = reinterpret_cast<const float4*>(pq)[s0 * 8 + c];
        ax += v0.x; ay += v0.y; az += v0.z; aw += v0.w;
    }
    float sc = 1.0f / fmaxf((float)deg, 1.0f);
    float4 q = reinterpret_cast<const float4*>(pq)[node * 8 + 4 + c];
    float4 r;
    r.x = ax * sc + q.x; r.y = ay * sc + q.y; r.z = az * sc + q.z; r.w = aw * sc + q.w;
    reinterpret_cast<float4*>(out)[node * 4 + c] = r;
}

extern "C" void kernel_launch(void* const* d_in, const int* in_sizes, int n_in,
                              void* d_out, int out_size, void* d_ws, size_t ws_size,
                              hipStream_t stream) {
    const float* x   = (const float*)d_in[0];
    const int*   ei  = (const int*)d_in[1];
    const float* W1l = (const float*)d_in[2];
    const float* W1r = (const float*)d_in[3];
    const float* b1  = (const float*)d_in[4];
    const float* W2l = (const float*)d_in[5];
    const float* W2r = (const float*)d_in[6];
    const float* b2  = (const float*)d_in[7];
    float* out = (float*)d_out;

    const int* src = ei;
    const int* dst = ei + NEDGES;

    // workspace layout
    int* cnt  = (int*)d_ws;                                                 // NP ints (degree)
    int* ebuf = cnt + NP;                                                   // N*SLOTS ints (12.8 MB)
    unsigned short* xb  = (unsigned short*)(ebuf + (size_t)NNODES * SLOTS); // N*128 bf16
    float* pq = (float*)(xb + (size_t)NNODES * HDIM);                       // N*32 f32
    unsigned short* w1img = (unsigned short*)(pq + (size_t)NNODES * 32);    // 32768 bf16 (2 halves)
    unsigned short* w2img = w1img + 32768;                                  // 4096 bf16

    hipMemsetAsync(cnt, 0, NP * sizeof(int), stream);

    binfuse_kernel<<<12500, 256, 0, stream>>>(src, dst, cnt, ebuf, x, xb,
                                              W1l, W1r, W2l, W2r, w1img, w2img);

    int ntiles1 = (NNODES + 63) / 64;   // 1563
    gemm_fused_kernel<<<ntiles1, 256, 0, stream>>>(xb, cnt, ebuf, w1img, w2img, b1, b2, pq);

    gather2_kernel<<<(NNODES * 4 + 255) / 256, 256, 0, stream>>>(pq, cnt, ebuf, out);
}